// Round 5
// baseline (5372.666 us; speedup 1.0000x reference)
//
#include <hip/hip_runtime.h>

#define TSTEPS 2048
#define PPB 16          // paths per block
#define NT 512          // 8 waves: m = wv&1 (MLP), nt = wv>>1 (column tile)
#define KAPPA 2.72f
#define THETA -3.5f

typedef _Float16 half8 __attribute__((ext_vector_type(8)));
typedef float f32x4 __attribute__((ext_vector_type(4)));

__device__ __forceinline__ float ftanh(float x) {
    float e = exp2f(x * 2.8853900817779268f);          // exp(2x)
    return 1.0f - 2.0f * __builtin_amdgcn_rcpf(e + 1.0f);
}
__device__ __forceinline__ float fsigm(float x) {
    float e = exp2f(x * -1.4426950408889634f);         // exp(-x)
    return __builtin_amdgcn_rcpf(1.0f + e);
}
__device__ __forceinline__ f32x4 mm(half8 a, half8 b, f32x4 c) {
    return __builtin_amdgcn_mfma_f32_16x16x32_f16(a, b, c, 0, 0, 0);
}
__device__ __forceinline__ void wsplit(float v, _Float16& h, _Float16& l) {
    h = (_Float16)v; l = (_Float16)(v - (float)h);
}

// LDS f16 activation rows: [row 0..15][slot 0..7][elem 0..7], slot = chunk ^ (row&7).

__global__ __launch_bounds__(NT, 4) void sim_kernel(
    const float* __restrict__ init_var, const float* __restrict__ dtp,
    const float* __restrict__ dwg,
    const float* __restrict__ dW0, const float* __restrict__ dB0,
    const float* __restrict__ dW1, const float* __restrict__ dB1,
    const float* __restrict__ dW2, const float* __restrict__ dB2,
    const float* __restrict__ dW3, const float* __restrict__ dB3,
    const float* __restrict__ fW0, const float* __restrict__ fB0,
    const float* __restrict__ fW1, const float* __restrict__ fB1,
    const float* __restrict__ fW2, const float* __restrict__ fB2,
    const float* __restrict__ fW3, const float* __restrict__ fB3,
    float* __restrict__ out)
{
    __shared__ __align__(16) _Float16 hA[2][1024];
    __shared__ __align__(16) _Float16 hB[2][1024];
    __shared__ __align__(16) _Float16 hC[2][1024];

    const int tid  = threadIdx.x;
    const int lane = tid & 63;
    const int wv   = tid >> 6;        // 0..7
    const int m    = wv & 1;          // which MLP this wave computes (0=drift,1=diff)
    const int nt   = wv >> 1;         // 0..3 column tile
    const int l15  = lane & 15;
    const int lg   = lane >> 4;       // 0..3
    const int col  = nt * 16 + l15;   // column within own MLP
    const int q    = l15 & 7;

    const int roff0 = l15 * 64 + ((lg ^ q) << 3);         // chunks 0-3 (K 0..31)
    const int roff1 = l15 * 64 + (((4 + lg) ^ q) << 3);   // chunks 4-7 (K 32..63)
    int woff[4];
#pragma unroll
    for (int r = 0; r < 4; ++r) {
        const int wrow = lg * 4 + r;
        woff[r] = wrow * 64 + ((((col >> 3) ^ (wrow & 7))) << 3) + (col & 7);
    }

    // own-MLP weight pointers
    const float* W0 = m ? fW0 : dW0;
    const float* B0 = m ? fB0 : dB0;
    const float* W1 = m ? fW1 : dW1;
    const float* B1 = m ? fB1 : dB1;
    const float* W2 = m ? fW2 : dW2;
    const float* B2 = m ? fB2 : dB2;

    // ---------------- B-fragments (own MLP) ----------------
    // L0 packed-K: A has K0..15 = x_hi, K16..31 = x_lo; two MFMAs with (Whi, Wlo)
    // give exact (xhi+xlo)*(Whi+Wlo) = x*W in f32.
    half8 b0h, b0l;
#pragma unroll
    for (int i = 0; i < 8; ++i) {
        const int idx = (lg & 1) * 8 + i;
        const float v = (idx < 15) ? W0[col * 15 + idx] : 0.f;
        _Float16 h, l; wsplit(v, h, l);
        b0h[i] = h; b0l[i] = l;
    }
    half8 b1h0, b1l0, b1h1, b1l1, b2h0, b2l0, b2h1, b2l1;
#pragma unroll
    for (int i = 0; i < 8; ++i) {
        const int ka = lg * 8 + i, kb = 32 + lg * 8 + i;
        _Float16 h, l;
        wsplit(W1[col * 64 + ka], h, l); b1h0[i] = h; b1l0[i] = l;
        wsplit(W1[col * 64 + kb], h, l); b1h1[i] = h; b1l1[i] = l;
        wsplit(W2[col * 64 + ka], h, l); b2h0[i] = h; b2l0[i] = l;
        wsplit(W2[col * 64 + kb], h, l); b2h1[i] = h; b2l1[i] = l;
    }
    // L3 fragments for BOTH MLPs (column 0 = w3)
    half8 w3d0, w3d1, w3f0, w3f1;
#pragma unroll
    for (int i = 0; i < 8; ++i) {
        const int ka = lg * 8 + i, kb = 32 + lg * 8 + i;
        w3d0[i] = (l15 == 0) ? (_Float16)dW3[ka] : (_Float16)0.f;
        w3d1[i] = (l15 == 0) ? (_Float16)dW3[kb] : (_Float16)0.f;
        w3f0[i] = (l15 == 0) ? (_Float16)fW3[ka] : (_Float16)0.f;
        w3f1[i] = (l15 == 0) ? (_Float16)fW3[kb] : (_Float16)0.f;
    }
    const float bias0 = B0[col], bias1 = B1[col], bias2 = B2[col];
    const float b3d = dB3[0], b3f = fB3[0];
    const float dt  = dtp[0];

    // ---------------- replicated per-lane state (p = lane&15) ----------------
    const int p = l15;
    const int path = blockIdx.x * PPB + p;
    const size_t pathT = (size_t)path * TSTEPS;
    float iv = fminf(fmaxf(init_var[path], 0.01f), 1.5f);
    float lv = __logf(iv);
    float s1a0 = 0.f, s1a1 = 0.f;
    float s2a0 = 0.f, s2a1 = 0.f, s2a2 = 0.f, s2a3 = 0.f;
    float s3a0 = 0.f, s3a1 = 0.f, s3a2 = 0.f, s3a3 = 0.f;
    float s3a4 = 0.f, s3a5 = 0.f, s3a6 = 0.f, s3a7 = 0.f;

    const bool selHi = (lg & 1) != 0;   // this lane's A-frag covers x[8..15]
    const bool selLo = (lg >> 1) != 0;  // this lane's A-frag carries the lo split

    for (int t = 0; t < TSTEPS; ++t) {
        const float dwv = dwg[pathT + t];

        // ---- build L0 A-fragment in-register from own state ----
        half8 a0;
        {
            const float xv0 = selHi ? s3a2 : s1a0;
            const float xv1 = selHi ? s3a3 : s1a1;
            const float xv2 = selHi ? s3a4 : s2a0;
            const float xv3 = selHi ? s3a5 : s2a1;
            const float xv4 = selHi ? s3a6 : s2a2;
            const float xv5 = selHi ? s3a7 : s2a3;
            const float xv6 = selHi ? (lv + 4.0f) : s3a0;
            const float xv7 = selHi ? 0.f : s3a1;
            _Float16 h, l;
            wsplit(xv0, h, l); a0[0] = selLo ? l : h;
            wsplit(xv1, h, l); a0[1] = selLo ? l : h;
            wsplit(xv2, h, l); a0[2] = selLo ? l : h;
            wsplit(xv3, h, l); a0[3] = selLo ? l : h;
            wsplit(xv4, h, l); a0[4] = selLo ? l : h;
            wsplit(xv5, h, l); a0[5] = selLo ? l : h;
            wsplit(xv6, h, l); a0[6] = selLo ? l : h;
            wsplit(xv7, h, l); a0[7] = selLo ? l : h;
        }

        // ---- L0: x -> h0 (own MLP, 2 MFMA, exact) ----
        {
            f32x4 c = {bias0, bias0, bias0, bias0};
            c = mm(a0, b0h, c);
            c = mm(a0, b0l, c);
#pragma unroll
            for (int r = 0; r < 4; ++r) hA[m][woff[r]] = (_Float16)ftanh(c[r]);
        }
        __syncthreads();

        // ---- L1: h0 -> h1 (own MLP, hi+lo weights) ----
        {
            const half8 a1 = *(const half8*)(&hA[m][roff0]);
            const half8 a2 = *(const half8*)(&hA[m][roff1]);
            f32x4 ca = {bias1, bias1, bias1, bias1};
            f32x4 cb = {0.f, 0.f, 0.f, 0.f};
            ca = mm(a1, b1h0, ca);  cb = mm(a1, b1l0, cb);
            ca = mm(a2, b1h1, ca);  cb = mm(a2, b1l1, cb);
            const f32x4 c = ca + cb;
#pragma unroll
            for (int r = 0; r < 4; ++r) hB[m][woff[r]] = (_Float16)ftanh(c[r]);
        }
        __syncthreads();

        // ---- L2: h1 -> h2 (own MLP) ----
        {
            const half8 a1 = *(const half8*)(&hB[m][roff0]);
            const half8 a2 = *(const half8*)(&hB[m][roff1]);
            f32x4 ca = {bias2, bias2, bias2, bias2};
            f32x4 cb = {0.f, 0.f, 0.f, 0.f};
            ca = mm(a1, b2h0, ca);  cb = mm(a1, b2l0, cb);
            ca = mm(a2, b2h1, ca);  cb = mm(a2, b2l1, cb);
            const f32x4 c = ca + cb;
#pragma unroll
            for (int r = 0; r < 4; ++r) hC[m][woff[r]] = (_Float16)ftanh(c[r]);
        }
        __syncthreads();

        // ---- L3 (every wave, both MLPs): h2 . w3 via MFMA col 0 ----
        float od, of;
        {
            const half8 ad0 = *(const half8*)(&hC[0][roff0]);
            const half8 ad1 = *(const half8*)(&hC[0][roff1]);
            const half8 af0 = *(const half8*)(&hC[1][roff0]);
            const half8 af1 = *(const half8*)(&hC[1][roff1]);
            f32x4 c3d = {0.f, 0.f, 0.f, 0.f}, c3f = {0.f, 0.f, 0.f, 0.f};
            c3d = mm(ad0, w3d0, c3d);  c3f = mm(af0, w3f0, c3f);
            c3d = mm(ad1, w3d1, c3d);  c3f = mm(af1, w3f1, c3f);
            const int src = (p >> 2) << 4;   // lane holding C[p][0], reg p&3
            const float gd0 = __shfl(c3d[0], src), gd1 = __shfl(c3d[1], src);
            const float gd2 = __shfl(c3d[2], src), gd3 = __shfl(c3d[3], src);
            const float gf0 = __shfl(c3f[0], src), gf1 = __shfl(c3f[1], src);
            const float gf2 = __shfl(c3f[2], src), gf3 = __shfl(c3f[3], src);
            od = ((p & 2) ? ((p & 1) ? gd3 : gd2) : ((p & 1) ? gd1 : gd0)) + b3d;
            of = ((p & 2) ? ((p & 1) ? gf3 : gf2) : ((p & 1) ? gf1 : gf0)) + b3f;
        }

        // ---- replicated state update (all lanes) ----
        {
            const float drift_nn = 0.5f * ftanh(od);
            const float diffu = 1.5f * fsigm(of) + 0.1f;
            float lvn = lv + KAPPA * (THETA - lv) * dt + drift_nn * dt + diffu * dwv;
            lvn = fminf(fmaxf(lvn, -5.0f), 1.0f);
            const float d = lvn - lv;
            const float o0 = dt * dt, o1 = dt * d, o2 = d * dt, o3 = d * d;
            const float c6 = 1.0f / 6.0f;
            s3a0 += s2a0 * dt + s1a0 * 0.5f * o0 + dt * o0 * c6;
            s3a1 += s2a0 * d  + s1a0 * 0.5f * o1 + dt * o1 * c6;
            s3a2 += s2a1 * dt + s1a0 * 0.5f * o2 + dt * o2 * c6;
            s3a3 += s2a1 * d  + s1a0 * 0.5f * o3 + dt * o3 * c6;
            s3a4 += s2a2 * dt + s1a1 * 0.5f * o0 + d * o0 * c6;
            s3a5 += s2a2 * d  + s1a1 * 0.5f * o1 + d * o1 * c6;
            s3a6 += s2a3 * dt + s1a1 * 0.5f * o2 + d * o2 * c6;
            s3a7 += s2a3 * d  + s1a1 * 0.5f * o3 + d * o3 * c6;
            s2a0 += s1a0 * dt + 0.5f * o0;  s2a1 += s1a0 * d + 0.5f * o1;
            s2a2 += s1a1 * dt + 0.5f * o2;  s2a3 += s1a1 * d + 0.5f * o3;
            s1a0 += dt;  s1a1 += d;
            if (tid < 16) out[pathT + t] = __expf(lvn);   // wave 0 stores
            lv = lvn;
        }
        // next L0 writes hA: safe — passing B3(t) implies all waves finished
        // their L1 reads of hA (pre-B2). hB/hC similarly protected by B1/B2.
    }
}

extern "C" void kernel_launch(void* const* d_in, const int* in_sizes, int n_in,
                              void* d_out, int out_size, void* d_ws, size_t ws_size,
                              hipStream_t stream) {
    const float* init_var = (const float*)d_in[0];
    const float* dtp      = (const float*)d_in[1];
    const float* dwg      = (const float*)d_in[2];
    const float* dW0 = (const float*)d_in[3];
    const float* dB0 = (const float*)d_in[4];
    const float* dW1 = (const float*)d_in[5];
    const float* dB1 = (const float*)d_in[6];
    const float* dW2 = (const float*)d_in[7];
    const float* dB2 = (const float*)d_in[8];
    const float* dW3 = (const float*)d_in[9];
    const float* dB3 = (const float*)d_in[10];
    const float* fW0 = (const float*)d_in[11];
    const float* fB0 = (const float*)d_in[12];
    const float* fW1 = (const float*)d_in[13];
    const float* fB1 = (const float*)d_in[14];
    const float* fW2 = (const float*)d_in[15];
    const float* fB2 = (const float*)d_in[16];
    const float* fW3 = (const float*)d_in[17];
    const float* fB3 = (const float*)d_in[18];
    float* out = (float*)d_out;

    sim_kernel<<<dim3(8192 / PPB), dim3(NT), 0, stream>>>(
        init_var, dtp, dwg,
        dW0, dB0, dW1, dB1, dW2, dB2, dW3, dB3,
        fW0, fB0, fW1, fB1, fW2, fB2, fW3, fB3,
        out);
}

// Round 6
// 4256.734 us; speedup vs baseline: 1.2622x; 1.2622x over previous
//
#include <hip/hip_runtime.h>

#define TSTEPS 2048
#define PPB 16          // paths per block
#define NT 256          // 4 waves; wave wv = column tile; each wave does BOTH MLPs
#define KAPPA 2.72f
#define THETA -3.5f

typedef _Float16 half8 __attribute__((ext_vector_type(8)));
typedef float f32x4 __attribute__((ext_vector_type(4)));

__device__ __forceinline__ float ftanh(float x) {
    float e = exp2f(x * 2.8853900817779268f);          // exp(2x)
    return 1.0f - 2.0f * __builtin_amdgcn_rcpf(e + 1.0f);
}
__device__ __forceinline__ float fsigm(float x) {
    float e = exp2f(x * -1.4426950408889634f);         // exp(-x)
    return __builtin_amdgcn_rcpf(1.0f + e);
}
__device__ __forceinline__ f32x4 mm(half8 a, half8 b, f32x4 c) {
    return __builtin_amdgcn_mfma_f32_16x16x32_f16(a, b, c, 0, 0, 0);
}
__device__ __forceinline__ void wsplit(float v, _Float16& h, _Float16& l) {
    h = (_Float16)v; l = (_Float16)(v - (float)h);
}

// LDS f16 activation rows: [row 0..15][slot 0..7][elem 0..7], slot = chunk ^ (row&7).

__global__ __launch_bounds__(NT, 2) void sim_kernel(
    const float* __restrict__ init_var, const float* __restrict__ dtp,
    const float* __restrict__ dwg,
    const float* __restrict__ dW0, const float* __restrict__ dB0,
    const float* __restrict__ dW1, const float* __restrict__ dB1,
    const float* __restrict__ dW2, const float* __restrict__ dB2,
    const float* __restrict__ dW3, const float* __restrict__ dB3,
    const float* __restrict__ fW0, const float* __restrict__ fB0,
    const float* __restrict__ fW1, const float* __restrict__ fB1,
    const float* __restrict__ fW2, const float* __restrict__ fB2,
    const float* __restrict__ fW3, const float* __restrict__ fB3,
    float* __restrict__ out)
{
    __shared__ __align__(16) _Float16 hA[2][1024];
    __shared__ __align__(16) _Float16 hB[2][1024];
    __shared__ __align__(16) _Float16 hC[2][1024];

    const int tid  = threadIdx.x;
    const int lane = tid & 63;
    const int wv   = tid >> 6;        // 0..3 column tile
    const int l15  = lane & 15;
    const int lg   = lane >> 4;       // 0..3
    const int col  = wv * 16 + l15;   // column this lane supplies (B) / owns (C)
    const int q    = l15 & 7;

    const int roff0 = l15 * 64 + ((lg ^ q) << 3);         // chunks 0-3 (K 0..31)
    const int roff1 = l15 * 64 + (((4 + lg) ^ q) << 3);   // chunks 4-7 (K 32..63)
    int woff[4];
#pragma unroll
    for (int r = 0; r < 4; ++r) {
        const int wrow = lg * 4 + r;
        woff[r] = wrow * 64 + ((((col >> 3) ^ (wrow & 7))) << 3) + (col & 7);
    }

    // ---------------- B-fragments (both MLPs) ----------------
    // L0 packed-K: A has K0..15 = x_hi, K16..31 = x_lo; 2 MFMAs (Whi, Wlo) per MLP = exact.
    half8 bd0h, bd0l, bf0h, bf0l;
#pragma unroll
    for (int i = 0; i < 8; ++i) {
        const int idx = (lg & 1) * 8 + i;
        const float vd = (idx < 15) ? dW0[col * 15 + idx] : 0.f;
        const float vf = (idx < 15) ? fW0[col * 15 + idx] : 0.f;
        _Float16 h, l;
        wsplit(vd, h, l); bd0h[i] = h; bd0l[i] = l;
        wsplit(vf, h, l); bf0h[i] = h; bf0l[i] = l;
    }
    half8 bd1h0, bd1l0, bd1h1, bd1l1, bd2h0, bd2l0, bd2h1, bd2l1;
    half8 bf1h0, bf1l0, bf1h1, bf1l1, bf2h0, bf2l0, bf2h1, bf2l1;
#pragma unroll
    for (int i = 0; i < 8; ++i) {
        const int ka = lg * 8 + i, kb = 32 + lg * 8 + i;
        _Float16 h, l;
        wsplit(dW1[col * 64 + ka], h, l); bd1h0[i] = h; bd1l0[i] = l;
        wsplit(dW1[col * 64 + kb], h, l); bd1h1[i] = h; bd1l1[i] = l;
        wsplit(dW2[col * 64 + ka], h, l); bd2h0[i] = h; bd2l0[i] = l;
        wsplit(dW2[col * 64 + kb], h, l); bd2h1[i] = h; bd2l1[i] = l;
        wsplit(fW1[col * 64 + ka], h, l); bf1h0[i] = h; bf1l0[i] = l;
        wsplit(fW1[col * 64 + kb], h, l); bf1h1[i] = h; bf1l1[i] = l;
        wsplit(fW2[col * 64 + ka], h, l); bf2h0[i] = h; bf2l0[i] = l;
        wsplit(fW2[col * 64 + kb], h, l); bf2h1[i] = h; bf2l1[i] = l;
    }
    // L3 A-fragments: A[r][k] = w3[k] for ALL rows r (lane-row-invariant) ->
    // C[r][p] = sum_k w3[k]*h2[p][k] = od[p] in EVERY lane with l15=p. No shuffles.
    half8 w3d0, w3d1, w3f0, w3f1;
#pragma unroll
    for (int i = 0; i < 8; ++i) {
        const int ka = lg * 8 + i, kb = 32 + lg * 8 + i;
        w3d0[i] = (_Float16)dW3[ka];
        w3d1[i] = (_Float16)dW3[kb];
        w3f0[i] = (_Float16)fW3[ka];
        w3f1[i] = (_Float16)fW3[kb];
    }
    const float biasd0 = dB0[col], biasd1 = dB1[col], biasd2 = dB2[col];
    const float biasf0 = fB0[col], biasf1 = fB1[col], biasf2 = fB2[col];
    const float b3d = dB3[0], b3f = fB3[0];
    const float dt  = dtp[0];

    // ---------------- replicated per-lane state (p = l15) ----------------
    const int p = l15;
    const int path = blockIdx.x * PPB + p;
    const size_t pathT = (size_t)path * TSTEPS;
    const float* dwp = dwg + pathT;
    float iv = fminf(fmaxf(init_var[path], 0.01f), 1.5f);
    float lv = __logf(iv);
    float s1a0 = 0.f, s1a1 = 0.f;
    float s2a0 = 0.f, s2a1 = 0.f, s2a2 = 0.f, s2a3 = 0.f;
    float s3a0 = 0.f, s3a1 = 0.f, s3a2 = 0.f, s3a3 = 0.f;
    float s3a4 = 0.f, s3a5 = 0.f, s3a6 = 0.f, s3a7 = 0.f;

    const bool selHi = (lg & 1) != 0;   // lane's L0 A-frag covers x[8..15]
    const bool selLo = (lg & 2) != 0;   // lane's L0 A-frag carries the lo split

    for (int t = 0; t < TSTEPS; ++t) {
        const float dwv = dwp[t];

        // ---- build L0 A-fragment in-register from own state ----
        half8 a0;
        {
            float xv[8];
            xv[0] = selHi ? s3a2 : s1a0;
            xv[1] = selHi ? s3a3 : s1a1;
            xv[2] = selHi ? s3a4 : s2a0;
            xv[3] = selHi ? s3a5 : s2a1;
            xv[4] = selHi ? s3a6 : s2a2;
            xv[5] = selHi ? s3a7 : s2a3;
            xv[6] = selHi ? (lv + 4.0f) : s3a0;
            xv[7] = selHi ? 0.f : s3a1;
#pragma unroll
            for (int i = 0; i < 8; ++i) {
                _Float16 h, l; wsplit(xv[i], h, l);
                a0[i] = selLo ? l : h;
            }
        }

        // ---- L0: x -> h0 (both MLPs, 2 MFMA each, exact) ----
        {
            f32x4 cd = {biasd0, biasd0, biasd0, biasd0};
            f32x4 cf = {biasf0, biasf0, biasf0, biasf0};
            cd = mm(a0, bd0h, cd);  cf = mm(a0, bf0h, cf);
            cd = mm(a0, bd0l, cd);  cf = mm(a0, bf0l, cf);
#pragma unroll
            for (int r = 0; r < 4; ++r) {
                hA[0][woff[r]] = (_Float16)ftanh(cd[r]);
                hA[1][woff[r]] = (_Float16)ftanh(cf[r]);
            }
        }
        __syncthreads();

        // ---- L1: h0 -> h1 (hi+lo weights) ----
        {
            const half8 ad0 = *(const half8*)(&hA[0][roff0]);
            const half8 ad1 = *(const half8*)(&hA[0][roff1]);
            const half8 af0 = *(const half8*)(&hA[1][roff0]);
            const half8 af1 = *(const half8*)(&hA[1][roff1]);
            f32x4 cda = {biasd1, biasd1, biasd1, biasd1};
            f32x4 cfa = {biasf1, biasf1, biasf1, biasf1};
            f32x4 cdb = {0.f, 0.f, 0.f, 0.f}, cfb = {0.f, 0.f, 0.f, 0.f};
            cda = mm(ad0, bd1h0, cda);  cfa = mm(af0, bf1h0, cfa);
            cdb = mm(ad0, bd1l0, cdb);  cfb = mm(af0, bf1l0, cfb);
            cda = mm(ad1, bd1h1, cda);  cfa = mm(af1, bf1h1, cfa);
            cdb = mm(ad1, bd1l1, cdb);  cfb = mm(af1, bf1l1, cfb);
            const f32x4 cd = cda + cdb, cf = cfa + cfb;
#pragma unroll
            for (int r = 0; r < 4; ++r) {
                hB[0][woff[r]] = (_Float16)ftanh(cd[r]);
                hB[1][woff[r]] = (_Float16)ftanh(cf[r]);
            }
        }
        __syncthreads();

        // ---- L2: h1 -> h2 ----
        {
            const half8 ad0 = *(const half8*)(&hB[0][roff0]);
            const half8 ad1 = *(const half8*)(&hB[0][roff1]);
            const half8 af0 = *(const half8*)(&hB[1][roff0]);
            const half8 af1 = *(const half8*)(&hB[1][roff1]);
            f32x4 cda = {biasd2, biasd2, biasd2, biasd2};
            f32x4 cfa = {biasf2, biasf2, biasf2, biasf2};
            f32x4 cdb = {0.f, 0.f, 0.f, 0.f}, cfb = {0.f, 0.f, 0.f, 0.f};
            cda = mm(ad0, bd2h0, cda);  cfa = mm(af0, bf2h0, cfa);
            cdb = mm(ad0, bd2l0, cdb);  cfb = mm(af0, bf2l0, cfb);
            cda = mm(ad1, bd2h1, cda);  cfa = mm(af1, bf2h1, cfa);
            cdb = mm(ad1, bd2l1, cdb);  cfb = mm(af1, bf2l1, cfb);
            const f32x4 cd = cda + cdb, cf = cfa + cfb;
#pragma unroll
            for (int r = 0; r < 4; ++r) {
                hC[0][woff[r]] = (_Float16)ftanh(cd[r]);
                hC[1][woff[r]] = (_Float16)ftanh(cf[r]);
            }
        }
        __syncthreads();

        // ---- L3: od/of broadcast to all lanes via w3-replicated A ----
        float od, of;
        {
            const half8 bd0 = *(const half8*)(&hC[0][roff0]);
            const half8 bd1 = *(const half8*)(&hC[0][roff1]);
            const half8 bf0 = *(const half8*)(&hC[1][roff0]);
            const half8 bf1 = *(const half8*)(&hC[1][roff1]);
            f32x4 c3d = {0.f, 0.f, 0.f, 0.f}, c3f = {0.f, 0.f, 0.f, 0.f};
            c3d = mm(w3d0, bd0, c3d);  c3f = mm(w3f0, bf0, c3f);
            c3d = mm(w3d1, bd1, c3d);  c3f = mm(w3f1, bf1, c3f);
            od = c3d[0] + b3d;          // C[row r][col p]: same value for all r
            of = c3f[0] + b3f;
        }

        // ---- replicated state update (all lanes, p = l15) ----
        {
            const float drift_nn = 0.5f * ftanh(od);
            const float diffu = 1.5f * fsigm(of) + 0.1f;
            float lvn = lv + KAPPA * (THETA - lv) * dt + drift_nn * dt + diffu * dwv;
            lvn = fminf(fmaxf(lvn, -5.0f), 1.0f);
            const float d = lvn - lv;
            const float o0 = dt * dt, o1 = dt * d, o2 = d * dt, o3 = d * d;
            const float c6 = 1.0f / 6.0f;
            s3a0 += s2a0 * dt + s1a0 * 0.5f * o0 + dt * o0 * c6;
            s3a1 += s2a0 * d  + s1a0 * 0.5f * o1 + dt * o1 * c6;
            s3a2 += s2a1 * dt + s1a0 * 0.5f * o2 + dt * o2 * c6;
            s3a3 += s2a1 * d  + s1a0 * 0.5f * o3 + dt * o3 * c6;
            s3a4 += s2a2 * dt + s1a1 * 0.5f * o0 + d * o0 * c6;
            s3a5 += s2a2 * d  + s1a1 * 0.5f * o1 + d * o1 * c6;
            s3a6 += s2a3 * dt + s1a1 * 0.5f * o2 + d * o2 * c6;
            s3a7 += s2a3 * d  + s1a1 * 0.5f * o3 + d * o3 * c6;
            s2a0 += s1a0 * dt + 0.5f * o0;  s2a1 += s1a0 * d + 0.5f * o1;
            s2a2 += s1a1 * dt + 0.5f * o2;  s2a3 += s1a1 * d + 0.5f * o3;
            s1a0 += dt;  s1a1 += d;
            if (tid < 16) out[pathT + t] = __expf(lvn);   // wave 0, lanes 0-15
            lv = lvn;
        }
        // Race-freedom: hA(t+1) written after B3(t) while last hA read was pre-B2(t);
        // hB(t+1) written after B1(t+1), last read pre-B3(t); hC(t+1) written after
        // B2(t+1), last read (L3) is pre-B1(t+1) in every wave's program order.
    }
}

extern "C" void kernel_launch(void* const* d_in, const int* in_sizes, int n_in,
                              void* d_out, int out_size, void* d_ws, size_t ws_size,
                              hipStream_t stream) {
    const float* init_var = (const float*)d_in[0];
    const float* dtp      = (const float*)d_in[1];
    const float* dwg      = (const float*)d_in[2];
    const float* dW0 = (const float*)d_in[3];
    const float* dB0 = (const float*)d_in[4];
    const float* dW1 = (const float*)d_in[5];
    const float* dB1 = (const float*)d_in[6];
    const float* dW2 = (const float*)d_in[7];
    const float* dB2 = (const float*)d_in[8];
    const float* dW3 = (const float*)d_in[9];
    const float* dB3 = (const float*)d_in[10];
    const float* fW0 = (const float*)d_in[11];
    const float* fB0 = (const float*)d_in[12];
    const float* fW1 = (const float*)d_in[13];
    const float* fB1 = (const float*)d_in[14];
    const float* fW2 = (const float*)d_in[15];
    const float* fB2 = (const float*)d_in[16];
    const float* fW3 = (const float*)d_in[17];
    const float* fB3 = (const float*)d_in[18];
    float* out = (float*)d_out;

    sim_kernel<<<dim3(8192 / PPB), dim3(NT), 0, stream>>>(
        init_var, dtp, dwg,
        dW0, dB0, dW1, dB1, dW2, dB2, dW3, dB3,
        fW0, fB0, fW1, fB1, fW2, fB2, fW3, fB3,
        out);
}

// Round 7
// 4001.232 us; speedup vs baseline: 1.3428x; 1.0639x over previous
//
#include <hip/hip_runtime.h>

#define TSTEPS 2048
#define PPB 16          // paths per block
#define NT 256          // 4 waves; wave wv = column tile; each wave does BOTH MLPs
#define KAPPA 2.72f
#define THETA -3.5f

typedef _Float16 half8 __attribute__((ext_vector_type(8)));
typedef float f32x4 __attribute__((ext_vector_type(4)));

__device__ __forceinline__ float ftanh(float x) {
    float e = exp2f(x * 2.8853900817779268f);          // exp(2x)
    return 1.0f - 2.0f * __builtin_amdgcn_rcpf(e + 1.0f);
}
__device__ __forceinline__ float fsigm(float x) {
    float e = exp2f(x * -1.4426950408889634f);         // exp(-x)
    return __builtin_amdgcn_rcpf(1.0f + e);
}
__device__ __forceinline__ f32x4 mm(half8 a, half8 b, f32x4 c) {
    return __builtin_amdgcn_mfma_f32_16x16x32_f16(a, b, c, 0, 0, 0);
}
__device__ __forceinline__ void wsplit(float v, _Float16& h, _Float16& l) {
    h = (_Float16)v; l = (_Float16)(v - (float)h);
}

// LDS f16 activation rows: [row 0..15][slot 0..7][elem 0..7], slot = chunk ^ (row&7).

__global__ __launch_bounds__(NT, 2) void sim_kernel(
    const float* __restrict__ init_var, const float* __restrict__ dtp,
    const float* __restrict__ dwg,
    const float* __restrict__ dW0, const float* __restrict__ dB0,
    const float* __restrict__ dW1, const float* __restrict__ dB1,
    const float* __restrict__ dW2, const float* __restrict__ dB2,
    const float* __restrict__ dW3, const float* __restrict__ dB3,
    const float* __restrict__ fW0, const float* __restrict__ fB0,
    const float* __restrict__ fW1, const float* __restrict__ fB1,
    const float* __restrict__ fW2, const float* __restrict__ fB2,
    const float* __restrict__ fW3, const float* __restrict__ fB3,
    float* __restrict__ out)
{
    __shared__ __align__(16) _Float16 hA[2][1024];
    __shared__ __align__(16) _Float16 hB[2][1024];
    __shared__ __align__(16) _Float16 hC[2][1024];

    const int tid  = threadIdx.x;
    const int lane = tid & 63;
    const int wv   = tid >> 6;        // 0..3 column tile
    const int l15  = lane & 15;
    const int lg   = lane >> 4;       // 0..3
    const int col  = wv * 16 + l15;   // column this lane supplies (B) / owns (C)
    const int q    = l15 & 7;

    const int roff0 = l15 * 64 + ((lg ^ q) << 3);         // chunks 0-3 (K 0..31)
    const int roff1 = l15 * 64 + (((4 + lg) ^ q) << 3);   // chunks 4-7 (K 32..63)
    int woff[4];
#pragma unroll
    for (int r = 0; r < 4; ++r) {
        const int wrow = lg * 4 + r;
        woff[r] = wrow * 64 + ((((col >> 3) ^ (wrow & 7))) << 3) + (col & 7);
    }

    // ---------------- B-fragments: 16 half8 = 64 VGPR (fits resident) ----------------
    // L0 packed-K (hi/lo exact): A has K0..15 = x_hi, K16..31 = x_lo;
    // two MFMAs (W0hi, W0lo) give exact x*W0 in f32.
    half8 bd0h, bd0l, bf0h, bf0l;
#pragma unroll
    for (int i = 0; i < 8; ++i) {
        const int idx = (lg & 1) * 8 + i;
        const float vd = (idx < 15) ? dW0[col * 15 + idx] : 0.f;
        const float vf = (idx < 15) ? fW0[col * 15 + idx] : 0.f;
        _Float16 h, l;
        wsplit(vd, h, l); bd0h[i] = h; bd0l[i] = l;
        wsplit(vf, h, l); bf0h[i] = h; bf0l[i] = l;
    }
    // L1/L2: single-f16 weights (hi only). Quantization error ~2^-11 rel,
    // accumulated log_v impact ~1.5e-3 << 7.46e-3 threshold.
    half8 bd1h0, bd1h1, bd2h0, bd2h1;
    half8 bf1h0, bf1h1, bf2h0, bf2h1;
#pragma unroll
    for (int i = 0; i < 8; ++i) {
        const int ka = lg * 8 + i, kb = 32 + lg * 8 + i;
        bd1h0[i] = (_Float16)dW1[col * 64 + ka];
        bd1h1[i] = (_Float16)dW1[col * 64 + kb];
        bd2h0[i] = (_Float16)dW2[col * 64 + ka];
        bd2h1[i] = (_Float16)dW2[col * 64 + kb];
        bf1h0[i] = (_Float16)fW1[col * 64 + ka];
        bf1h1[i] = (_Float16)fW1[col * 64 + kb];
        bf2h0[i] = (_Float16)fW2[col * 64 + ka];
        bf2h1[i] = (_Float16)fW2[col * 64 + kb];
    }
    // L3 A-fragments: A[r][k] = w3[k] for ALL rows (lane-row-invariant) ->
    // C[r][p] = od[p] in every lane with l15=p. No shuffles.
    half8 w3d0, w3d1, w3f0, w3f1;
#pragma unroll
    for (int i = 0; i < 8; ++i) {
        const int ka = lg * 8 + i, kb = 32 + lg * 8 + i;
        w3d0[i] = (_Float16)dW3[ka];
        w3d1[i] = (_Float16)dW3[kb];
        w3f0[i] = (_Float16)fW3[ka];
        w3f1[i] = (_Float16)fW3[kb];
    }
    const float biasd0 = dB0[col], biasd1 = dB1[col], biasd2 = dB2[col];
    const float biasf0 = fB0[col], biasf1 = fB1[col], biasf2 = fB2[col];
    const float b3d = dB3[0], b3f = fB3[0];
    const float dt  = dtp[0];

    // ---------------- replicated per-lane state (p = l15) ----------------
    const int p = l15;
    const int path = blockIdx.x * PPB + p;
    const size_t pathT = (size_t)path * TSTEPS;
    const float* dwp = dwg + pathT;
    float iv = fminf(fmaxf(init_var[path], 0.01f), 1.5f);
    float lv = __logf(iv);
    float s1a0 = 0.f, s1a1 = 0.f;
    float s2a0 = 0.f, s2a1 = 0.f, s2a2 = 0.f, s2a3 = 0.f;
    float s3a0 = 0.f, s3a1 = 0.f, s3a2 = 0.f, s3a3 = 0.f;
    float s3a4 = 0.f, s3a5 = 0.f, s3a6 = 0.f, s3a7 = 0.f;

    const bool selHi = (lg & 1) != 0;   // lane's L0 A-frag covers x[8..15]
    const bool selLo = (lg & 2) != 0;   // lane's L0 A-frag carries the lo split

    for (int t = 0; t < TSTEPS; ++t) {
        const float dwv = dwp[t];

        // ---- build L0 A-fragment in-register from own state ----
        half8 a0;
        {
            float xv[8];
            xv[0] = selHi ? s3a2 : s1a0;
            xv[1] = selHi ? s3a3 : s1a1;
            xv[2] = selHi ? s3a4 : s2a0;
            xv[3] = selHi ? s3a5 : s2a1;
            xv[4] = selHi ? s3a6 : s2a2;
            xv[5] = selHi ? s3a7 : s2a3;
            xv[6] = selHi ? (lv + 4.0f) : s3a0;
            xv[7] = selHi ? 0.f : s3a1;
#pragma unroll
            for (int i = 0; i < 8; ++i) {
                _Float16 h, l; wsplit(xv[i], h, l);
                a0[i] = selLo ? l : h;
            }
        }

        // ---- L0: x -> h0 (both MLPs, 2 MFMA each, exact hi/lo) ----
        {
            f32x4 cd = {biasd0, biasd0, biasd0, biasd0};
            f32x4 cf = {biasf0, biasf0, biasf0, biasf0};
            cd = mm(a0, bd0h, cd);  cf = mm(a0, bf0h, cf);
            cd = mm(a0, bd0l, cd);  cf = mm(a0, bf0l, cf);
#pragma unroll
            for (int r = 0; r < 4; ++r) {
                hA[0][woff[r]] = (_Float16)ftanh(cd[r]);
                hA[1][woff[r]] = (_Float16)ftanh(cf[r]);
            }
        }
        __syncthreads();

        // ---- L1: h0 -> h1 (f16 weights) ----
        {
            const half8 ad0 = *(const half8*)(&hA[0][roff0]);
            const half8 ad1 = *(const half8*)(&hA[0][roff1]);
            const half8 af0 = *(const half8*)(&hA[1][roff0]);
            const half8 af1 = *(const half8*)(&hA[1][roff1]);
            f32x4 cd = {biasd1, biasd1, biasd1, biasd1};
            f32x4 cf = {biasf1, biasf1, biasf1, biasf1};
            cd = mm(ad0, bd1h0, cd);  cf = mm(af0, bf1h0, cf);
            cd = mm(ad1, bd1h1, cd);  cf = mm(af1, bf1h1, cf);
#pragma unroll
            for (int r = 0; r < 4; ++r) {
                hB[0][woff[r]] = (_Float16)ftanh(cd[r]);
                hB[1][woff[r]] = (_Float16)ftanh(cf[r]);
            }
        }
        __syncthreads();

        // ---- L2: h1 -> h2 ----
        {
            const half8 ad0 = *(const half8*)(&hB[0][roff0]);
            const half8 ad1 = *(const half8*)(&hB[0][roff1]);
            const half8 af0 = *(const half8*)(&hB[1][roff0]);
            const half8 af1 = *(const half8*)(&hB[1][roff1]);
            f32x4 cd = {biasd2, biasd2, biasd2, biasd2};
            f32x4 cf = {biasf2, biasf2, biasf2, biasf2};
            cd = mm(ad0, bd2h0, cd);  cf = mm(af0, bf2h0, cf);
            cd = mm(ad1, bd2h1, cd);  cf = mm(af1, bf2h1, cf);
#pragma unroll
            for (int r = 0; r < 4; ++r) {
                hC[0][woff[r]] = (_Float16)ftanh(cd[r]);
                hC[1][woff[r]] = (_Float16)ftanh(cf[r]);
            }
        }
        __syncthreads();

        // ---- L3: od/of broadcast to all lanes via w3-replicated A ----
        float od, of;
        {
            const half8 bd0 = *(const half8*)(&hC[0][roff0]);
            const half8 bd1 = *(const half8*)(&hC[0][roff1]);
            const half8 bf0 = *(const half8*)(&hC[1][roff0]);
            const half8 bf1 = *(const half8*)(&hC[1][roff1]);
            f32x4 c3d = {0.f, 0.f, 0.f, 0.f}, c3f = {0.f, 0.f, 0.f, 0.f};
            c3d = mm(w3d0, bd0, c3d);  c3f = mm(w3f0, bf0, c3f);
            c3d = mm(w3d1, bd1, c3d);  c3f = mm(w3f1, bf1, c3f);
            od = c3d[0] + b3d;          // same value in all C rows
            of = c3f[0] + b3f;
        }

        // ---- replicated state update (all lanes, p = l15) ----
        {
            const float drift_nn = 0.5f * ftanh(od);
            const float diffu = 1.5f * fsigm(of) + 0.1f;
            float lvn = lv + KAPPA * (THETA - lv) * dt + drift_nn * dt + diffu * dwv;
            lvn = fminf(fmaxf(lvn, -5.0f), 1.0f);
            const float d = lvn - lv;
            const float o0 = dt * dt, o1 = dt * d, o2 = d * dt, o3 = d * d;
            const float c6 = 1.0f / 6.0f;
            s3a0 += s2a0 * dt + s1a0 * 0.5f * o0 + dt * o0 * c6;
            s3a1 += s2a0 * d  + s1a0 * 0.5f * o1 + dt * o1 * c6;
            s3a2 += s2a1 * dt + s1a0 * 0.5f * o2 + dt * o2 * c6;
            s3a3 += s2a1 * d  + s1a0 * 0.5f * o3 + dt * o3 * c6;
            s3a4 += s2a2 * dt + s1a1 * 0.5f * o0 + d * o0 * c6;
            s3a5 += s2a2 * d  + s1a1 * 0.5f * o1 + d * o1 * c6;
            s3a6 += s2a3 * dt + s1a1 * 0.5f * o2 + d * o2 * c6;
            s3a7 += s2a3 * d  + s1a1 * 0.5f * o3 + d * o3 * c6;
            s2a0 += s1a0 * dt + 0.5f * o0;  s2a1 += s1a0 * d + 0.5f * o1;
            s2a2 += s1a1 * dt + 0.5f * o2;  s2a3 += s1a1 * d + 0.5f * o3;
            s1a0 += dt;  s1a1 += d;
            if (tid < 16) out[pathT + t] = __expf(lvn);   // wave 0, lanes 0-15
            lv = lvn;
        }
        // Race-freedom: hA(t+1) written after B3(t), last hA read pre-B2(t);
        // hB(t+1) after B1(t+1), last read pre-B3(t); hC(t+1) after B2(t+1),
        // last read (L3) pre-B1(t+1) in every wave's program order.
    }
}

extern "C" void kernel_launch(void* const* d_in, const int* in_sizes, int n_in,
                              void* d_out, int out_size, void* d_ws, size_t ws_size,
                              hipStream_t stream) {
    const float* init_var = (const float*)d_in[0];
    const float* dtp      = (const float*)d_in[1];
    const float* dwg      = (const float*)d_in[2];
    const float* dW0 = (const float*)d_in[3];
    const float* dB0 = (const float*)d_in[4];
    const float* dW1 = (const float*)d_in[5];
    const float* dB1 = (const float*)d_in[6];
    const float* dW2 = (const float*)d_in[7];
    const float* dB2 = (const float*)d_in[8];
    const float* dW3 = (const float*)d_in[9];
    const float* dB3 = (const float*)d_in[10];
    const float* fW0 = (const float*)d_in[11];
    const float* fB0 = (const float*)d_in[12];
    const float* fW1 = (const float*)d_in[13];
    const float* fB1 = (const float*)d_in[14];
    const float* fW2 = (const float*)d_in[15];
    const float* fB2 = (const float*)d_in[16];
    const float* fW3 = (const float*)d_in[17];
    const float* fB3 = (const float*)d_in[18];
    float* out = (float*)d_out;

    sim_kernel<<<dim3(8192 / PPB), dim3(NT), 0, stream>>>(
        init_var, dtp, dwg,
        dW0, dB0, dW1, dB1, dW2, dB2, dW3, dB3,
        fW0, fB0, fW1, fB1, fW2, fB2, fW3, fB3,
        out);
}

// Round 8
// 3347.899 us; speedup vs baseline: 1.6048x; 1.1951x over previous
//
#include <hip/hip_runtime.h>

#define TSTEPS 2048
#define PPB 16          // paths per block
#define NT 256          // 4 waves; wave wv = column tile; each wave does BOTH MLPs
#define KAPPA 2.72f
#define THETA -3.5f

typedef _Float16 half8 __attribute__((ext_vector_type(8)));
typedef float f32x4 __attribute__((ext_vector_type(4)));

__device__ __forceinline__ float ftanh(float x) {
    float e = __expf(2.0f * x);                        // v_mul + v_exp_f32 (native)
    return 1.0f - 2.0f * __builtin_amdgcn_rcpf(e + 1.0f);
}
__device__ __forceinline__ float fsigm(float x) {
    float e = __expf(-x);
    return __builtin_amdgcn_rcpf(1.0f + e);
}
__device__ __forceinline__ f32x4 mm(half8 a, half8 b, f32x4 c) {
    return __builtin_amdgcn_mfma_f32_16x16x32_f16(a, b, c, 0, 0, 0);
}
__device__ __forceinline__ void wsplit(float v, _Float16& h, _Float16& l) {
    h = (_Float16)v; l = (_Float16)(v - (float)h);
}

// LDS f16 activation rows: [row 0..15][slot 0..7][elem 0..7], slot = chunk ^ (row&7).

__global__ __launch_bounds__(NT, 2) void sim_kernel(
    const float* __restrict__ init_var, const float* __restrict__ dtp,
    const float* __restrict__ dwg,
    const float* __restrict__ dW0, const float* __restrict__ dB0,
    const float* __restrict__ dW1, const float* __restrict__ dB1,
    const float* __restrict__ dW2, const float* __restrict__ dB2,
    const float* __restrict__ dW3, const float* __restrict__ dB3,
    const float* __restrict__ fW0, const float* __restrict__ fB0,
    const float* __restrict__ fW1, const float* __restrict__ fB1,
    const float* __restrict__ fW2, const float* __restrict__ fB2,
    const float* __restrict__ fW3, const float* __restrict__ fB3,
    float* __restrict__ out)
{
    __shared__ __align__(16) _Float16 hA[2][1024];
    __shared__ __align__(16) _Float16 hB[2][1024];
    __shared__ __align__(16) _Float16 hC[2][1024];

    const int tid  = threadIdx.x;
    const int lane = tid & 63;
    const int wv   = tid >> 6;        // 0..3 column tile
    const int l15  = lane & 15;
    const int lg   = lane >> 4;       // 0..3
    const int col  = wv * 16 + l15;   // column this lane supplies (B) / owns (C)
    const int q    = l15 & 7;

    const int roff0 = l15 * 64 + ((lg ^ q) << 3);         // chunks 0-3 (K 0..31)
    const int roff1 = l15 * 64 + (((4 + lg) ^ q) << 3);   // chunks 4-7 (K 32..63)
    int woff[4];
#pragma unroll
    for (int r = 0; r < 4; ++r) {
        const int wrow = lg * 4 + r;
        woff[r] = wrow * 64 + ((((col >> 3) ^ (wrow & 7))) << 3) + (col & 7);
    }

    // ---------------- B-fragments: 16 half8 = 64 VGPR ----------------
    // L0 packed-K (hi/lo exact): A has K0..15 = x_hi, K16..31 = x_lo;
    // two MFMAs (W0hi, W0lo) give exact x*W0 in f32.
    half8 bd0h, bd0l, bf0h, bf0l;
#pragma unroll
    for (int i = 0; i < 8; ++i) {
        const int idx = (lg & 1) * 8 + i;
        const float vd = (idx < 15) ? dW0[col * 15 + idx] : 0.f;
        const float vf = (idx < 15) ? fW0[col * 15 + idx] : 0.f;
        _Float16 h, l;
        wsplit(vd, h, l); bd0h[i] = h; bd0l[i] = l;
        wsplit(vf, h, l); bf0h[i] = h; bf0l[i] = l;
    }
    // L1/L2: single-f16 weights (hi only); ~2^-11 rel error, well inside budget.
    half8 bd1h0, bd1h1, bd2h0, bd2h1;
    half8 bf1h0, bf1h1, bf2h0, bf2h1;
#pragma unroll
    for (int i = 0; i < 8; ++i) {
        const int ka = lg * 8 + i, kb = 32 + lg * 8 + i;
        bd1h0[i] = (_Float16)dW1[col * 64 + ka];
        bd1h1[i] = (_Float16)dW1[col * 64 + kb];
        bd2h0[i] = (_Float16)dW2[col * 64 + ka];
        bd2h1[i] = (_Float16)dW2[col * 64 + kb];
        bf1h0[i] = (_Float16)fW1[col * 64 + ka];
        bf1h1[i] = (_Float16)fW1[col * 64 + kb];
        bf2h0[i] = (_Float16)fW2[col * 64 + ka];
        bf2h1[i] = (_Float16)fW2[col * 64 + kb];
    }
    // L3 A-fragments: A[r][k] = w3[k] for ALL rows -> C[r][p] = od[p], no shuffles.
    half8 w3d0, w3d1, w3f0, w3f1;
#pragma unroll
    for (int i = 0; i < 8; ++i) {
        const int ka = lg * 8 + i, kb = 32 + lg * 8 + i;
        w3d0[i] = (_Float16)dW3[ka];
        w3d1[i] = (_Float16)dW3[kb];
        w3f0[i] = (_Float16)fW3[ka];
        w3f1[i] = (_Float16)fW3[kb];
    }
    // Pin all weight fragments as opaque asm outputs: the loads + f16 splits
    // above can no longer be rematerialized inside the t-loop.
    asm volatile("" : "+v"(bd0h), "+v"(bd0l), "+v"(bf0h), "+v"(bf0l));
    asm volatile("" : "+v"(bd1h0), "+v"(bd1h1), "+v"(bd2h0), "+v"(bd2h1));
    asm volatile("" : "+v"(bf1h0), "+v"(bf1h1), "+v"(bf2h0), "+v"(bf2h1));
    asm volatile("" : "+v"(w3d0), "+v"(w3d1), "+v"(w3f0), "+v"(w3f1));

    const float biasd0 = dB0[col], biasd1 = dB1[col], biasd2 = dB2[col];
    const float biasf0 = fB0[col], biasf1 = fB1[col], biasf2 = fB2[col];
    const float b3d = dB3[0], b3f = fB3[0];
    const float dt  = dtp[0];

    // ---------------- replicated per-lane state (p = l15) ----------------
    const int p = l15;
    const int path = blockIdx.x * PPB + p;
    const size_t pathT = (size_t)path * TSTEPS;
    const float* dwp = dwg + pathT;
    float iv = fminf(fmaxf(init_var[path], 0.01f), 1.5f);
    float lv = __logf(iv);
    float s1a0 = 0.f, s1a1 = 0.f;
    float s2a0 = 0.f, s2a1 = 0.f, s2a2 = 0.f, s2a3 = 0.f;
    float s3a0 = 0.f, s3a1 = 0.f, s3a2 = 0.f, s3a3 = 0.f;
    float s3a4 = 0.f, s3a5 = 0.f, s3a6 = 0.f, s3a7 = 0.f;

    const bool selHi = (lg & 1) != 0;   // lane's L0 A-frag covers x[8..15]
    const bool selLo = (lg & 2) != 0;   // lane's L0 A-frag carries the lo split

    for (int t = 0; t < TSTEPS; ++t) {
        const float dwv = dwp[t];

        // ---- build L0 A-fragment in-register from own state ----
        half8 a0;
        {
            float xv[8];
            xv[0] = selHi ? s3a2 : s1a0;
            xv[1] = selHi ? s3a3 : s1a1;
            xv[2] = selHi ? s3a4 : s2a0;
            xv[3] = selHi ? s3a5 : s2a1;
            xv[4] = selHi ? s3a6 : s2a2;
            xv[5] = selHi ? s3a7 : s2a3;
            xv[6] = selHi ? (lv + 4.0f) : s3a0;
            xv[7] = selHi ? 0.f : s3a1;
#pragma unroll
            for (int i = 0; i < 8; ++i) {
                _Float16 h, l; wsplit(xv[i], h, l);
                a0[i] = selLo ? l : h;
            }
        }

        // ---- L0: x -> h0 (both MLPs, 2 MFMA each, exact hi/lo) ----
        {
            f32x4 cd = {biasd0, biasd0, biasd0, biasd0};
            f32x4 cf = {biasf0, biasf0, biasf0, biasf0};
            cd = mm(a0, bd0h, cd);  cf = mm(a0, bf0h, cf);
            cd = mm(a0, bd0l, cd);  cf = mm(a0, bf0l, cf);
#pragma unroll
            for (int r = 0; r < 4; ++r) {
                hA[0][woff[r]] = (_Float16)ftanh(cd[r]);
                hA[1][woff[r]] = (_Float16)ftanh(cf[r]);
            }
        }
        __syncthreads();

        // ---- L1: h0 -> h1 (f16 weights) ----
        {
            const half8 ad0 = *(const half8*)(&hA[0][roff0]);
            const half8 ad1 = *(const half8*)(&hA[0][roff1]);
            const half8 af0 = *(const half8*)(&hA[1][roff0]);
            const half8 af1 = *(const half8*)(&hA[1][roff1]);
            f32x4 cd = {biasd1, biasd1, biasd1, biasd1};
            f32x4 cf = {biasf1, biasf1, biasf1, biasf1};
            cd = mm(ad0, bd1h0, cd);  cf = mm(af0, bf1h0, cf);
            cd = mm(ad1, bd1h1, cd);  cf = mm(af1, bf1h1, cf);
#pragma unroll
            for (int r = 0; r < 4; ++r) {
                hB[0][woff[r]] = (_Float16)ftanh(cd[r]);
                hB[1][woff[r]] = (_Float16)ftanh(cf[r]);
            }
        }
        __syncthreads();

        // ---- L2: h1 -> h2 ----
        {
            const half8 ad0 = *(const half8*)(&hB[0][roff0]);
            const half8 ad1 = *(const half8*)(&hB[0][roff1]);
            const half8 af0 = *(const half8*)(&hB[1][roff0]);
            const half8 af1 = *(const half8*)(&hB[1][roff1]);
            f32x4 cd = {biasd2, biasd2, biasd2, biasd2};
            f32x4 cf = {biasf2, biasf2, biasf2, biasf2};
            cd = mm(ad0, bd2h0, cd);  cf = mm(af0, bf2h0, cf);
            cd = mm(ad1, bd2h1, cd);  cf = mm(af1, bf2h1, cf);
#pragma unroll
            for (int r = 0; r < 4; ++r) {
                hC[0][woff[r]] = (_Float16)ftanh(cd[r]);
                hC[1][woff[r]] = (_Float16)ftanh(cf[r]);
            }
        }
        __syncthreads();

        // ---- L3: od/of broadcast to all lanes via w3-replicated A ----
        float od, of;
        {
            const half8 bd0 = *(const half8*)(&hC[0][roff0]);
            const half8 bd1 = *(const half8*)(&hC[0][roff1]);
            const half8 bf0 = *(const half8*)(&hC[1][roff0]);
            const half8 bf1 = *(const half8*)(&hC[1][roff1]);
            f32x4 c3d = {0.f, 0.f, 0.f, 0.f}, c3f = {0.f, 0.f, 0.f, 0.f};
            c3d = mm(w3d0, bd0, c3d);  c3f = mm(w3f0, bf0, c3f);
            c3d = mm(w3d1, bd1, c3d);  c3f = mm(w3f1, bf1, c3f);
            od = c3d[0] + b3d;          // same value in all C rows
            of = c3f[0] + b3f;
        }

        // ---- replicated state update (all lanes, p = l15) ----
        {
            const float drift_nn = 0.5f * ftanh(od);
            const float diffu = 1.5f * fsigm(of) + 0.1f;
            float lvn = lv + KAPPA * (THETA - lv) * dt + drift_nn * dt + diffu * dwv;
            lvn = fminf(fmaxf(lvn, -5.0f), 1.0f);
            const float d = lvn - lv;
            const float o0 = dt * dt, o1 = dt * d, o2 = d * dt, o3 = d * d;
            const float c6 = 1.0f / 6.0f;
            s3a0 += s2a0 * dt + s1a0 * 0.5f * o0 + dt * o0 * c6;
            s3a1 += s2a0 * d  + s1a0 * 0.5f * o1 + dt * o1 * c6;
            s3a2 += s2a1 * dt + s1a0 * 0.5f * o2 + dt * o2 * c6;
            s3a3 += s2a1 * d  + s1a0 * 0.5f * o3 + dt * o3 * c6;
            s3a4 += s2a2 * dt + s1a1 * 0.5f * o0 + d * o0 * c6;
            s3a5 += s2a2 * d  + s1a1 * 0.5f * o1 + d * o1 * c6;
            s3a6 += s2a3 * dt + s1a1 * 0.5f * o2 + d * o2 * c6;
            s3a7 += s2a3 * d  + s1a1 * 0.5f * o3 + d * o3 * c6;
            s2a0 += s1a0 * dt + 0.5f * o0;  s2a1 += s1a0 * d + 0.5f * o1;
            s2a2 += s1a1 * dt + 0.5f * o2;  s2a3 += s1a1 * d + 0.5f * o3;
            s1a0 += dt;  s1a1 += d;
            if (tid < 16) out[pathT + t] = __expf(lvn);   // wave 0, lanes 0-15
            lv = lvn;
        }
        // Race-freedom: hA(t+1) written after B3(t), last hA read pre-B2(t);
        // hB(t+1) after B1(t+1), last read pre-B3(t); hC(t+1) after B2(t+1),
        // last read (L3) pre-B1(t+1) in every wave's program order.
    }
}

extern "C" void kernel_launch(void* const* d_in, const int* in_sizes, int n_in,
                              void* d_out, int out_size, void* d_ws, size_t ws_size,
                              hipStream_t stream) {
    const float* init_var = (const float*)d_in[0];
    const float* dtp      = (const float*)d_in[1];
    const float* dwg      = (const float*)d_in[2];
    const float* dW0 = (const float*)d_in[3];
    const float* dB0 = (const float*)d_in[4];
    const float* dW1 = (const float*)d_in[5];
    const float* dB1 = (const float*)d_in[6];
    const float* dW2 = (const float*)d_in[7];
    const float* dB2 = (const float*)d_in[8];
    const float* dW3 = (const float*)d_in[9];
    const float* dB3 = (const float*)d_in[10];
    const float* fW0 = (const float*)d_in[11];
    const float* fB0 = (const float*)d_in[12];
    const float* fW1 = (const float*)d_in[13];
    const float* fB1 = (const float*)d_in[14];
    const float* fW2 = (const float*)d_in[15];
    const float* fB2 = (const float*)d_in[16];
    const float* fW3 = (const float*)d_in[17];
    const float* fB3 = (const float*)d_in[18];
    float* out = (float*)d_out;

    sim_kernel<<<dim3(8192 / PPB), dim3(NT), 0, stream>>>(
        init_var, dtp, dwg,
        dW0, dB0, dW1, dB1, dW2, dB2, dW3, dB3,
        fW0, fB0, fW1, fB1, fW2, fB2, fW3, fB3,
        out);
}